// Round 1
// baseline (584.208 us; speedup 1.0000x reference)
//
#include <hip/hip_runtime.h>
#include <math.h>

typedef _Float16 f16;
typedef _Float16 f16x8 __attribute__((ext_vector_type(8)));
typedef float f32x4 __attribute__((ext_vector_type(4)));

#define HH 32
#define WW 64
#define NPX 2048
#define SLOTS 68          // 64 px + 2 halo each side
// lo-planes pre-scaled by 2^11 to stay in fp16 NORMAL range (denormal inputs
// are flushed by the MFMA pipe -- proven by earlier bit-identical failure)
#define LOSCALE 2048.0f
#define INV_LOSCALE 4.8828125e-4f

typedef const __attribute__((address_space(1))) void gvoid;
typedef __attribute__((address_space(3))) void lvoid;
__device__ __forceinline__ void gload_lds16(const void* g, void* l) {
    __builtin_amdgcn_global_load_lds((gvoid*)g, (lvoid*)l, 16, 0, 0);
}

// ---- zero halo act buffers (P|Q|X0 contiguous in ws; re-poisoned every call)
__global__ void zero_kernel(f16* p, int n8) {
    int i = blockIdx.x * 256 + threadIdx.x;
    if (i < n8) *(int4*)(p + i * 8) = make_int4(0, 0, 0, 0);
}

// ---- prep: X0 halo buffer [row][slot][ci=64], hi=(data-3.5)*mask (exact), lo=0
__global__ void prep_kernel(const float* __restrict__ data,
                            const float* __restrict__ mask,
                            f16* __restrict__ X0, int plane) {
    int idx = blockIdx.x * 256 + threadIdx.x;      // px*64 + ci
    if (idx >= NPX * 64) return;
    int px = idx >> 6, ci = idx & 63;
    int hh = px >> 6, w = px & 63;
    float v = (data[ci * NPX + px] - 3.5f) * mask[ci * NPX + px];
    int dst = ((hh + 2) * SLOTS + (w + 2)) * 64 + ci;
    X0[dst] = (f16)v;
    X0[plane + dst] = (f16)0.f;
}

// ---- repack: WP[0][tap][co_p][ci]=fp16(w_masked); WP[1]=fp16((w-hi)*2048)
// is_out: co_p = g*2+c -> orig co = g*3+1+c (mu,sig only; logits provably unused)
__global__ void repack_kernel(const float* __restrict__ W, f16* __restrict__ WP,
                              int cin_log2, int coutp_log2,
                              int cpg_in_log2, int limb, int is_out) {
    int idx = blockIdx.x * 256 + threadIdx.x;
    int Cin = 1 << cin_log2;
    int plane = 25 << (cin_log2 + coutp_log2);
    int ci = idx & (Cin - 1);
    int rest = idx >> cin_log2;
    int co_p = rest & ((1 << coutp_log2) - 1);
    int tap = rest >> coutp_log2;
    if (tap >= 25) return;
    int ky = tap / 5, kx = tap - 5 * ky;
    int co_orig, g_out;
    if (is_out) { g_out = co_p >> 1; co_orig = 3 * g_out + 1 + (co_p & 1); }
    else        { g_out = co_p >> 2; co_orig = co_p; }
    int g_in = ci >> cpg_in_log2;
    float v = 0.f;
    if (ky + kx <= limb + g_out - g_in)
        v = W[(co_orig * Cin + ci) * 25 + tap];
    f16 vh = (f16)v;
    WP[idx] = vh;
    WP[plane + idx] = (f16)((v - (float)vh) * LOSCALE);
}

// ---- fused conv V2: implicit GEMM, split-fp16, ky-per-wave.
// Wave tile 32co x 32px (2 A-frags x 2 B-frags of mfma_f32_16x16x32_f16):
// each B ds_read now feeds 2 co-tiles -> LDS-read pipe (20 reads/chunk, ~240cy)
// drops below the MFMA pipe (60 mfma/chunk, ~291cy). Double-buffered LDS
// staging with counted s_waitcnt vmcnt(5) + raw s_barrier: next chunk's
// global_load_lds stay in flight across the barrier (no vmcnt(0) drain).
// grid = nmt*32*2 blocks (8mt x 32h x 2 w-slabs); complementary-mt pairing:
// block b and b+nmt*32 land on the same CU (round-robin) and get mt/nmt-1-mt
// whose K-chunk counts sum to a near-constant -> balanced + latency overlap.
__global__ __launch_bounds__(320, 2) void conv_kernel(
    const f16* __restrict__ IN, int Cin, int inPlane,
    const f16* __restrict__ WP, int wPlane,
    const float* __restrict__ bias,
    const f16* __restrict__ RES, int resPlane,
    f16* __restrict__ OA, int oaPlane,
    float* __restrict__ OT,
    int nmt, int Coutp, int cpg_out, int cpg_in, int limb, int mode)
{
    // 2 x 25600B staging buffers: [pl2][row5][slot36][ci32] f16 = 23040B + pad
    __shared__ __align__(16) char SMEM[51200];
    f16* BL = (f16*)SMEM;
    float* RED = (float*)SMEM;     // [kw5][px32][co pad36] = 23040 B after loop

    const int t = threadIdx.x;
    const int kw = t >> 6;                 // wave index == ky
    const int lane = t & 63, l15 = lane & 15, q = lane >> 4;

    // balanced mapping: b < half -> (mt, h, slab0); else (nmt-1-mt, h, slab1)
    int b = blockIdx.x;
    int half = nmt << 5;
    int sl = b >= half ? 1 : 0;
    int idx = b - (sl ? half : 0);
    int mtRaw = idx >> 5;
    const int h = idx & 31;
    const int mt = sl ? (nmt - 1 - mtRaw) : mtRaw;
    const int co0 = mt * 32;
    const int px0 = sl * 32;
    const int g_max = (co0 + 31) / cpg_out;

    // masked K-extent per kx for this wave's ky (allowed iff ky+kx<=limb+g_out-g_in)
    int cnt[5];
#pragma unroll
    for (int kx = 0; kx < 5; kx++) {
        int c = (g_max + limb - (kw + kx) + 1) * cpg_in;
        c = c < Cin ? c : Cin;
        cnt[kx] = c > 0 ? c : 0;
    }
    int ci_top = (g_max + limb + 1) * cpg_in;   // block-uniform chunk bound
    ci_top = ci_top < Cin ? ci_top : Cin;
    const int NT = (ci_top + 31) >> 5;

    // per-lane staging sources: 1440 16B-units = [pl2][row5][slot36][ci16x2]
    // all waves issue exactly 5 rounds (uniform vmcnt count); tail lanes write pad
    const f16* src[5];
#pragma unroll
    for (int r = 0; r < 5; r++) {
        int u = r * 320 + t;
        if (u >= 1440) u = 0;              // tail lanes: any valid addr (dest=pad)
        int pl = u >= 720 ? 1 : 0;
        int rem = u - pl * 720;
        int row = rem / 144;
        int rr = rem - row * 144;
        int slt = rr >> 2, c16 = rr & 3;
        src[r] = IN + (size_t)pl * inPlane
               + ((h + row) * SLOTS + px0 + slt) * Cin + c16 * 8;
    }

    f32x4 acc_h[2][2], acc_m[2][2];
#pragma unroll
    for (int i = 0; i < 2; i++)
#pragma unroll
        for (int j = 0; j < 2; j++) {
            acc_h[i][j] = (f32x4){0.f, 0.f, 0.f, 0.f};
            acc_m[i][j] = (f32x4){0.f, 0.f, 0.f, 0.f};
        }

    const size_t kxs = (size_t)Coutp * Cin;
    const f16* wb0 = WP + ((size_t)(kw * 5) * Coutp + co0) * Cin + q * 8;

    // prologue: stage chunk 0 -> buf 0
#pragma unroll
    for (int r = 0; r < 5; r++)
        gload_lds16(src[r], BL + (r * 320 + kw * 64) * 8);

    for (int it = 0; it < NT; ++it) {
        const int ci0 = it << 5;
        f16* buf = BL + (it & 1) * 12800;
        if (it + 1 < NT) {
            // issue next chunk into the other buffer; loads stay in flight
            f16* nb = BL + ((it & 1) ^ 1) * 12800;
#pragma unroll
            for (int r = 0; r < 5; r++)
                gload_lds16(src[r] + ci0 + 32, nb + (r * 320 + kw * 64) * 8);
            asm volatile("s_waitcnt vmcnt(5)" ::: "memory");  // cur chunk landed
        } else {
            asm volatile("s_waitcnt vmcnt(0)" ::: "memory");
        }
        __builtin_amdgcn_s_barrier();
        asm volatile("" ::: "memory");

        // A frags straight from global (L2-resident), depth-1 prefetch over kx
        const f16* wb = wb0 + ci0;
        const f16* bhp = buf + kw * 1152 + q * 8;          // [slot36][ci32] rows
        const f16* blp = buf + (5 + kw) * 1152 + q * 8;
        f16x8 cah0, cah1, cal0, cal1, nah0, nah1, nal0, nal1;
        if (ci0 < cnt[0]) {
            cah0 = *(const f16x8*)(wb + l15 * Cin);
            cah1 = *(const f16x8*)(wb + (16 + l15) * Cin);
            cal0 = *(const f16x8*)(wb + wPlane + l15 * Cin);
            cal1 = *(const f16x8*)(wb + wPlane + (16 + l15) * Cin);
        }
#pragma unroll
        for (int kx = 0; kx < 5; kx++) {
            if (ci0 >= cnt[kx]) break;     // cnt non-increasing in kx, wave-uniform
            if (kx < 4 && ci0 < cnt[kx + 1]) {
                const f16* nwb = wb + (kx + 1) * kxs;
                nah0 = *(const f16x8*)(nwb + l15 * Cin);
                nah1 = *(const f16x8*)(nwb + (16 + l15) * Cin);
                nal0 = *(const f16x8*)(nwb + wPlane + l15 * Cin);
                nal1 = *(const f16x8*)(nwb + wPlane + (16 + l15) * Cin);
            }
            f16x8 bh0 = *(const f16x8*)(bhp + (l15 + kx) * 32);
            f16x8 bh1 = *(const f16x8*)(bhp + (16 + l15 + kx) * 32);
            f16x8 bl0 = *(const f16x8*)(blp + (l15 + kx) * 32);
            f16x8 bl1 = *(const f16x8*)(blp + (16 + l15 + kx) * 32);
            acc_h[0][0] = __builtin_amdgcn_mfma_f32_16x16x32_f16(cah0, bh0, acc_h[0][0], 0, 0, 0);
            acc_h[0][1] = __builtin_amdgcn_mfma_f32_16x16x32_f16(cah0, bh1, acc_h[0][1], 0, 0, 0);
            acc_h[1][0] = __builtin_amdgcn_mfma_f32_16x16x32_f16(cah1, bh0, acc_h[1][0], 0, 0, 0);
            acc_h[1][1] = __builtin_amdgcn_mfma_f32_16x16x32_f16(cah1, bh1, acc_h[1][1], 0, 0, 0);
            acc_m[0][0] = __builtin_amdgcn_mfma_f32_16x16x32_f16(cah0, bl0, acc_m[0][0], 0, 0, 0);
            acc_m[0][1] = __builtin_amdgcn_mfma_f32_16x16x32_f16(cah0, bl1, acc_m[0][1], 0, 0, 0);
            acc_m[1][0] = __builtin_amdgcn_mfma_f32_16x16x32_f16(cah1, bl0, acc_m[1][0], 0, 0, 0);
            acc_m[1][1] = __builtin_amdgcn_mfma_f32_16x16x32_f16(cah1, bl1, acc_m[1][1], 0, 0, 0);
            acc_m[0][0] = __builtin_amdgcn_mfma_f32_16x16x32_f16(cal0, bh0, acc_m[0][0], 0, 0, 0);
            acc_m[0][1] = __builtin_amdgcn_mfma_f32_16x16x32_f16(cal0, bh1, acc_m[0][1], 0, 0, 0);
            acc_m[1][0] = __builtin_amdgcn_mfma_f32_16x16x32_f16(cal1, bh0, acc_m[1][0], 0, 0, 0);
            acc_m[1][1] = __builtin_amdgcn_mfma_f32_16x16x32_f16(cal1, bh1, acc_m[1][1], 0, 0, 0);
            cah0 = nah0; cah1 = nah1; cal0 = nal0; cal1 = nal1;
        }
        __builtin_amdgcn_s_barrier();      // all reads of buf done before overwrite
        asm volatile("" ::: "memory");
    }

    // in-block ky reduction through LDS (C/D: px=j*16+l15, co=i*16+q*4+r)
#pragma unroll
    for (int i = 0; i < 2; i++)
#pragma unroll
        for (int j = 0; j < 2; j++) {
            f32x4 v;
#pragma unroll
            for (int r = 0; r < 4; r++)
                v[r] = acc_h[i][j][r] + acc_m[i][j][r] * INV_LOSCALE;
            *(f32x4*)&RED[(kw * 32 + j * 16 + l15) * 36 + i * 16 + q * 4] = v;
        }
    __syncthreads();

    if (mode == 0) {
        // bias + relu (+ residual) -> split-f16 halo store (C=Coutp layout)
        for (int c = t; c < 1024; c += 320) {
            int px = c >> 5, col = c & 31;
            float v = bias[co0 + col];
#pragma unroll
            for (int k5 = 0; k5 < 5; k5++) v += RED[(k5 * 32 + px) * 36 + col];
            v = fmaxf(v, 0.f);
            int o = ((h + 2) * SLOTS + px0 + px + 2) * Coutp + co0 + col;
            if (RES) v += (float)RES[o] + (float)RES[resPlane + o] * INV_LOSCALE;
            f16 vh = (f16)v;
            OA[o] = vh;
            OA[oaPlane + o] = (f16)((v - (float)vh) * LOSCALE);
        }
    } else {
        // output conv: co_p = g*2 + {mu,sig}; fold bias+softplus+erf table here
        for (int c = t; c < 1024; c += 320) {
            int px = c >> 5, col = c & 31;
            float v = bias[3 * ((co0 + col) >> 1) + 1 + (col & 1)];
#pragma unroll
            for (int k5 = 0; k5 < 5; k5++) v += RED[(k5 * 32 + px) * 36 + col];
            RED[px * 36 + col] = v;    // own-cell write after own-cell reads: safe
        }
        __syncthreads();
        for (int c = t; c < 512; c += 320) {
            int px = c >> 4, gl = c & 15;
            float mu = RED[px * 36 + 2 * gl];
            float s  = RED[px * 36 + 2 * gl + 1];
            float sp = fmaxf(s, 0.f) + log1pf(expf(-fabsf(s)));
            float sig = sp + 1e-6f;
            float inv = 1.f / (sig * 1.41421356237f);
            int g = (co0 >> 1) + gl;
            float* o = OT + ((size_t)g * NPX + h * WW + px0 + px) * 8;
#pragma unroll
            for (int k = 0; k < 8; k++) {
                float z = ((float)k - 3.0f - mu) * inv;
                o[k] = 32768.f * (1.f + erff(z));
            }
        }
    }
}

extern "C" void kernel_launch(void* const* d_in, const int* in_sizes, int n_in,
                              void* d_out, int out_size, void* d_ws, size_t ws_size,
                              hipStream_t stream) {
    const float* data  = (const float*)d_in[0];
    const float* mask  = (const float*)d_in[1];
    const float* w_in  = (const float*)d_in[2];
    const float* b_in  = (const float*)d_in[3];
    const float* w_hid = (const float*)d_in[4];
    const float* b_hid = (const float*)d_in[5];
    const float* w_out = (const float*)d_in[6];
    const float* b_out = (const float*)d_in[7];
    float* out = (float*)d_out;

    // ws: WP 6.55MB | P 2.51 | Q 2.51 | X0 0.63  = 12.2 MB total
    f16* WP = (f16*)d_ws;                  // 2 x 25*256*256 f16
    f16* P  = WP + 3276800;                // 2 x 36*68*256 f16 (halo act, x)
    f16* Q  = P + 1253376;                 // 2 x 36*68*256 f16 (halo act, h1)
    f16* X0 = Q + 1253376;                 // 2 x 36*68*64 f16

    // zero P|Q|X0 (contiguous): 2,820,096 f16 = 352,512 x (8 f16)
    zero_kernel<<<1377, 256, 0, stream>>>(P, 352512);
    prep_kernel<<<512, 256, 0, stream>>>(data, mask, X0, 156672);

    // input conv: Cin=64, strict (limb=3), cpg_in=1 -> P
    repack_kernel<<<1600, 256, 0, stream>>>(w_in, WP, 6, 8, 0, 3, 0);
    conv_kernel<<<512, 320, 0, stream>>>(X0, 64, 156672, WP, 409600,
        b_in, nullptr, 0, P, 626688, nullptr, 8, 256, 4, 1, 3, 0);

    for (int i = 0; i < 5; i++) {
        repack_kernel<<<6400, 256, 0, stream>>>(w_hid + (size_t)(2 * i) * 1638400,
                                                WP, 8, 8, 2, 4, 0);
        conv_kernel<<<512, 320, 0, stream>>>(P, 256, 626688, WP, 1638400,
            b_hid + 2 * i * 256, nullptr, 0, Q, 626688, nullptr, 8, 256, 4, 4, 4, 0);
        repack_kernel<<<6400, 256, 0, stream>>>(w_hid + (size_t)(2 * i + 1) * 1638400,
                                                WP, 8, 8, 2, 4, 0);
        // conv2: residual x (P) added after relu, written back in-place to P
        conv_kernel<<<512, 320, 0, stream>>>(Q, 256, 626688, WP, 1638400,
            b_hid + (2 * i + 1) * 256, P, 626688, P, 626688, nullptr, 8, 256, 4, 4, 4, 0);
    }

    // output conv: mu/sig only (Coutp=128, cpg_out=2, limb=4) + fused erf table
    repack_kernel<<<3200, 256, 0, stream>>>(w_out, WP, 8, 7, 2, 4, 1);
    conv_kernel<<<256, 320, 0, stream>>>(P, 256, 626688, WP, 819200,
        b_out, nullptr, 0, nullptr, 0, out, 4, 128, 2, 4, 4, 1);
}

// Round 2
// 459.735 us; speedup vs baseline: 1.2707x; 1.2707x over previous
//
#include <hip/hip_runtime.h>
#include <math.h>

typedef _Float16 f16;
typedef _Float16 f16x8 __attribute__((ext_vector_type(8)));
typedef float f32x4 __attribute__((ext_vector_type(4)));

#define HH 32
#define WW 64
#define NPX 2048
#define SLOTS 68          // 64 px + 2 halo each side
#define CHS 78336         // 36*68*32 f16 = one 32-ci slab of the halo grid
// lo-planes pre-scaled by 2^11 to stay in fp16 NORMAL range (denormal inputs
// are flushed by the MFMA pipe -- proven by earlier bit-identical failure)
#define LOSCALE 2048.0f
#define INV_LOSCALE 4.8828125e-4f

typedef const __attribute__((address_space(1))) void gvoid;
typedef __attribute__((address_space(3))) void lvoid;
__device__ __forceinline__ void gload_lds16(const void* g, void* l) {
    __builtin_amdgcn_global_load_lds((gvoid*)g, (lvoid*)l, 16, 0, 0);
}

// ---- zero halo act buffers (P|Q|X0 contiguous in ws; re-poisoned every call)
__global__ void zero_kernel(f16* p, int n8) {
    int i = blockIdx.x * 256 + threadIdx.x;
    if (i < n8) *(int4*)(p + i * 8) = make_int4(0, 0, 0, 0);
}

// ---- prep: X0 halo buffer [cic][row][slot][ci32], hi=(data-3.5)*mask, lo=0
__global__ void prep_kernel(const float* __restrict__ data,
                            const float* __restrict__ mask,
                            f16* __restrict__ X0, int plane) {
    int idx = blockIdx.x * 256 + threadIdx.x;      // px*64 + ci
    if (idx >= NPX * 64) return;
    int px = idx >> 6, ci = idx & 63;
    int hh = px >> 6, w = px & 63;
    float v = (data[ci * NPX + px] - 3.5f) * mask[ci * NPX + px];
    int dst = (ci >> 5) * CHS + ((hh + 2) * SLOTS + (w + 2)) * 32 + (ci & 31);
    X0[dst] = (f16)v;
    X0[plane + dst] = (f16)0.f;
}

// ---- repack to fully-tiled layout: [tap25][coT=co/16][cic=ci/32][co16][ci32]
// -> each A-fragment (16co x 32ci) is one contiguous 1KB tile (lane-coalesced).
// hi plane at 0, lo plane (residual * 2048) at +plane.
// is_out: co_p = g*2+c -> orig co = g*3+1+c (mu,sig only; logits provably unused)
__global__ void repack_kernel(const float* __restrict__ W, f16* __restrict__ WP,
                              int cin_log2, int coutp_log2,
                              int cpg_in_log2, int limb, int is_out) {
    int idx = blockIdx.x * 256 + threadIdx.x;
    int Cin = 1 << cin_log2;
    int plane = 25 << (cin_log2 + coutp_log2);
    int ci = idx & (Cin - 1);
    int rest = idx >> cin_log2;
    int co_p = rest & ((1 << coutp_log2) - 1);
    int tap = rest >> coutp_log2;
    if (tap >= 25) return;
    int ky = tap / 5, kx = tap - 5 * ky;
    int co_orig, g_out;
    if (is_out) { g_out = co_p >> 1; co_orig = 3 * g_out + 1 + (co_p & 1); }
    else        { g_out = co_p >> 2; co_orig = co_p; }
    int g_in = ci >> cpg_in_log2;
    float v = 0.f;
    if (ky + kx <= limb + g_out - g_in)
        v = W[(co_orig * Cin + ci) * 25 + tap];
    f16 vh = (f16)v;
    int dst = (((tap << (coutp_log2 - 4)) + (co_p >> 4)) << (cin_log2 - 5 + 9))
            + ((ci >> 5) << 9) + ((co_p & 15) << 5) + (ci & 31);
    WP[dst] = vh;
    WP[plane + dst] = (f16)((v - (float)vh) * LOSCALE);
}

// ---- fused conv: implicit GEMM, split-fp16, ky-per-wave, in-kernel reduction.
// V3 = proven 497us structure + CONTIGUOUS global layouts:
//  - act [pl][cic][row][slot][ci32]: a chunk's stage region is one 21.8KB run
//    per plane -> each 64-lane global_load_lds reads 1KB consecutive.
//  - weights tiled per (tap, co-tile, cic): each A-frag load is 1KB consecutive.
// Previously both paths were 64B granules at 512B stride (L2 channel conflicts).
// grid = nmt*32 blocks (2 blocks/CU); complementary-mt pairing: block b and
// b+nmt*16 land on the same CU and get mt / nmt-1-mt -> balanced K-work.
// Block 320 thr = 5 waves; wave kw handles tap-row ky=kw; per-wave tile
// 16co x 64px via 1x4 frags of mfma_f32_16x16x32_f16, depth-1 A prefetch.
__global__ __launch_bounds__(320, 3) void conv_kernel(
    const f16* __restrict__ IN, int Cin, int inPlane,
    const f16* __restrict__ WP, int wPlane,
    const float* __restrict__ bias,
    const f16* __restrict__ RES, int resPlane,
    f16* __restrict__ OA, int oaPlane,
    float* __restrict__ OT,
    int nmt, int Coutp, int cpg_out, int cpg_in, int limb, int mode)
{
    __shared__ __align__(16) char SMEM[46080];
    f16* BL = (f16*)SMEM;      // [plane2][row5][slot68][ci32] = 43520 B (+pad)
    float* RED = (float*)SMEM; // [kw5][px64][co pad20] = 25600 B (after K loop)

    const int t = threadIdx.x;
    const int kw = t >> 6;                 // wave index == ky
    const int lane = t & 63, l15 = lane & 15, q = lane >> 4;

    // balanced mapping
    int b = blockIdx.x;
    int half = nmt << 4;
    int slot = b >= half ? 1 : 0;
    int idx = b - (slot ? half : 0);
    int mt8 = idx >> 5;
    const int h = idx & 31;
    const int mt = slot ? (nmt - 1 - mt8) : mt8;
    const int co0 = mt * 16;
    const int g_max = (co0 + 15) / cpg_out;

    // masked K-extent per kx for this wave's ky (allowed iff ky+kx<=limb+g_out-g_in)
    int cnt[5];
#pragma unroll
    for (int kx = 0; kx < 5; kx++) {
        int c = (g_max + limb - (kw + kx) + 1) * cpg_in;
        c = c < Cin ? c : Cin;
        cnt[kx] = c > 0 ? c : 0;
    }
    int ci_top = (g_max + limb + 1) * cpg_in;   // block-uniform chunk bound
    ci_top = ci_top < Cin ? ci_top : Cin;

    // per-lane staging sources: 2720 16B-units, linear in [pl][row5][slot68][ci32]
    // -> global addresses are CONSECUTIVE across lanes (contiguous 21.8KB/plane)
    const f16* src[9];
#pragma unroll
    for (int r = 0; r < 9; r++) {
        int u = r * 320 + t;
        if (u >= 2720) u = 0;              // tail lanes: any valid addr (dest=pad)
        int pl = u >= 1360 ? 1 : 0;
        int rem = u - pl * 1360;
        src[r] = IN + (size_t)pl * inPlane + h * 2176 + rem * 8;
    }

    f32x4 acc_h[4], acc_m[4];
#pragma unroll
    for (int j = 0; j < 4; j++) {
        acc_h[j] = (f32x4){0.f, 0.f, 0.f, 0.f};
        acc_m[j] = (f32x4){0.f, 0.f, 0.f, 0.f};
    }

    // tiled weight addressing: tile (tap, mt, cic) is 512 f16 contiguous
    const size_t kxs = (size_t)Coutp * Cin;            // per-kx tap stride
    const f16* wb0 = WP + (size_t)(kw * 5 * (Coutp >> 4) + mt) * ((size_t)Cin << 4)
                   + l15 * 32 + q * 8;

    int coff = 0;                                      // (ci0/32)*CHS
    for (int ci0 = 0; ci0 < ci_top; ci0 += 32, coff += CHS) {
        __syncthreads();
        // stage B: 43520 B = 9 rounds x 5 waves x 1024 B, direct global->LDS
#pragma unroll
        for (int r = 0; r < 9; r++) {
            int ub = r * 320 + kw * 64;
            if (ub < 2720)                 // wave-uniform (BL padded for overshoot)
                gload_lds16(src[r] + coff, BL + ub * 8);
        }
        __syncthreads();

        // A frags from global: contiguous 1KB tiles, depth-1 prefetch over kx
        const f16* wb = wb0 + (ci0 >> 5) * 512;
        f16x8 cah, cal, nah, nal;
        if (ci0 < cnt[0]) {
            cah = *(const f16x8*)(wb);
            cal = *(const f16x8*)(wb + wPlane);
        }
#pragma unroll
        for (int kx = 0; kx < 5; kx++) {
            if (ci0 >= cnt[kx]) break;     // cnt non-increasing in kx, wave-uniform
            if (kx < 4 && ci0 < cnt[kx + 1]) {
                nah = *(const f16x8*)(wb + (kx + 1) * kxs);
                nal = *(const f16x8*)(wb + (kx + 1) * kxs + wPlane);
            }
            f16x8 bh[4], bl[4];
#pragma unroll
            for (int j = 0; j < 4; j++) {
                int slt = j * 16 + l15 + kx;
                bh[j] = *(const f16x8*)&BL[(0 * 5 + kw) * (SLOTS * 32) + slt * 32 + q * 8];
                bl[j] = *(const f16x8*)&BL[(1 * 5 + kw) * (SLOTS * 32) + slt * 32 + q * 8];
            }
#pragma unroll
            for (int j = 0; j < 4; j++) {
                acc_h[j] = __builtin_amdgcn_mfma_f32_16x16x32_f16(cah, bh[j], acc_h[j], 0, 0, 0);
                acc_m[j] = __builtin_amdgcn_mfma_f32_16x16x32_f16(cah, bl[j], acc_m[j], 0, 0, 0);
                acc_m[j] = __builtin_amdgcn_mfma_f32_16x16x32_f16(cal, bh[j], acc_m[j], 0, 0, 0);
            }
            cah = nah; cal = nal;
        }
    }

    // in-block ky reduction through LDS (C/D layout: px=j*16+l15, co=q*4+r)
    __syncthreads();   // all BL reads done before RED aliases SMEM
#pragma unroll
    for (int j = 0; j < 4; j++) {
        f32x4 v;
#pragma unroll
        for (int r = 0; r < 4; r++)
            v[r] = acc_h[j][r] + acc_m[j][r] * INV_LOSCALE;
        *(f32x4*)&RED[(kw * 64 + j * 16 + l15) * 20 + q * 4] = v;
    }
    __syncthreads();

    if (mode == 0) {
        // bias + relu (+ residual) -> split-f16 halo store (chunk-major layout)
        for (int c = t; c < 1024; c += 320) {
            int px = c >> 4, col = c & 15;
            float v = bias[co0 + col];
#pragma unroll
            for (int k5 = 0; k5 < 5; k5++) v += RED[(k5 * 64 + px) * 20 + col];
            v = fmaxf(v, 0.f);
            int cc = co0 + col;
            int o = (cc >> 5) * CHS + ((h + 2) * SLOTS + px + 2) * 32 + (cc & 31);
            if (RES) v += (float)RES[o] + (float)RES[resPlane + o] * INV_LOSCALE;
            f16 vh = (f16)v;
            OA[o] = vh;
            OA[oaPlane + o] = (f16)((v - (float)vh) * LOSCALE);
        }
    } else {
        // output conv: co_p = g*2 + {mu,sig}; fold bias+softplus+erf table here
        for (int c = t; c < 1024; c += 320) {
            int px = c >> 4, col = c & 15;
            float v = bias[3 * ((co0 + col) >> 1) + 1 + (col & 1)];
#pragma unroll
            for (int k5 = 0; k5 < 5; k5++) v += RED[(k5 * 64 + px) * 20 + col];
            RED[px * 20 + col] = v;    // own-cell write after own-cell reads: safe
        }
        __syncthreads();
        for (int c = t; c < 512; c += 320) {
            int px = c >> 3, gl = c & 7;
            float mu = RED[px * 20 + 2 * gl];
            float s  = RED[px * 20 + 2 * gl + 1];
            float sp = fmaxf(s, 0.f) + log1pf(expf(-fabsf(s)));
            float sig = sp + 1e-6f;
            float inv = 1.f / (sig * 1.41421356237f);
            int g = (co0 >> 1) + gl;
            float* o = OT + ((size_t)g * NPX + h * WW + px) * 8;
#pragma unroll
            for (int k = 0; k < 8; k++) {
                float z = ((float)k - 3.0f - mu) * inv;
                o[k] = 32768.f * (1.f + erff(z));
            }
        }
    }
}

extern "C" void kernel_launch(void* const* d_in, const int* in_sizes, int n_in,
                              void* d_out, int out_size, void* d_ws, size_t ws_size,
                              hipStream_t stream) {
    const float* data  = (const float*)d_in[0];
    const float* mask  = (const float*)d_in[1];
    const float* w_in  = (const float*)d_in[2];
    const float* b_in  = (const float*)d_in[3];
    const float* w_hid = (const float*)d_in[4];
    const float* b_hid = (const float*)d_in[5];
    const float* w_out = (const float*)d_in[6];
    const float* b_out = (const float*)d_in[7];
    float* out = (float*)d_out;

    // ws: WP 6.55MB | P 2.51 | Q 2.51 | X0 0.63  = 12.2 MB total
    f16* WP = (f16*)d_ws;                  // 2 x 25*256*256 f16
    f16* P  = WP + 3276800;                // 2 x 8*CHS f16 (halo act, x)
    f16* Q  = P + 1253376;                 // 2 x 8*CHS f16 (halo act, h1)
    f16* X0 = Q + 1253376;                 // 2 x 2*CHS f16

    // zero P|Q|X0 (contiguous): 2,820,096 f16 = 352,512 x (8 f16)
    zero_kernel<<<1377, 256, 0, stream>>>(P, 352512);
    prep_kernel<<<512, 256, 0, stream>>>(data, mask, X0, 156672);

    // input conv: Cin=64, strict (limb=3), cpg_in=1 -> P
    repack_kernel<<<1600, 256, 0, stream>>>(w_in, WP, 6, 8, 0, 3, 0);
    conv_kernel<<<512, 320, 0, stream>>>(X0, 64, 156672, WP, 409600,
        b_in, nullptr, 0, P, 626688, nullptr, 16, 256, 4, 1, 3, 0);

    for (int i = 0; i < 5; i++) {
        repack_kernel<<<6400, 256, 0, stream>>>(w_hid + (size_t)(2 * i) * 1638400,
                                                WP, 8, 8, 2, 4, 0);
        conv_kernel<<<512, 320, 0, stream>>>(P, 256, 626688, WP, 1638400,
            b_hid + 2 * i * 256, nullptr, 0, Q, 626688, nullptr, 16, 256, 4, 4, 4, 0);
        repack_kernel<<<6400, 256, 0, stream>>>(w_hid + (size_t)(2 * i + 1) * 1638400,
                                                WP, 8, 8, 2, 4, 0);
        // conv2: residual x (P) added after relu, written back in-place to P
        conv_kernel<<<512, 320, 0, stream>>>(Q, 256, 626688, WP, 1638400,
            b_hid + (2 * i + 1) * 256, P, 626688, P, 626688, nullptr, 16, 256, 4, 4, 4, 0);
    }

    // output conv: mu/sig only (Coutp=128, cpg_out=2, limb=4) + fused erf table
    repack_kernel<<<3200, 256, 0, stream>>>(w_out, WP, 8, 7, 2, 4, 1);
    conv_kernel<<<256, 320, 0, stream>>>(P, 256, 626688, WP, 819200,
        b_out, nullptr, 0, nullptr, 0, out, 8, 128, 2, 4, 4, 1);
}